// Round 8
// baseline (226.987 us; speedup 1.0000x reference)
//
#include <hip/hip_runtime.h>
#include <stdint.h>
#include <stddef.h>

// ---------------------------------------------------------------------------
// EinsumSelfAttention: LN(x + Attn(xWq^T+bq, xWk^T+bk, xWv^T+bv) Wo^T + bo)
// B=2 T=2048 D=1024 H=16 dk=64.  All matmuls via bf16 MFMA 32x32x16.
// Layouts: C/D (verified m74/m101): col=lane&31, row=(reg&3)+8*(reg>>2)+4*(lane>>5)
//          A/B frag: lane holds X[row/col=lane&31][k=(lane>>5)*8+j], j=0..7
// attn: 8 waves = 4 row-groups x 2 s-halves (R7 lesson: 4-wave blocks ->
// 2 waves/SIMD starves latency hiding). Partial acc_o/li per s-half combine
// by addition at epilogue (fixed-max softmax => no rescale needed).
// K-loops: async-LDS double buffer via global_load_lds, one barrier per tile.
// NO register-held tile data (R5: per-thread prefetch arrays -> scratch spill).
// ---------------------------------------------------------------------------

typedef __bf16 bf16_t;
typedef bf16_t bf16x8 __attribute__((ext_vector_type(8)));
typedef float f32x16 __attribute__((ext_vector_type(16)));
typedef uint16_t u16x8 __attribute__((ext_vector_type(8)));

#define MFMA32(a, b, c) __builtin_amdgcn_mfma_f32_32x32x16_bf16((a), (b), (c), 0, 0, 0)

__device__ __forceinline__ uint16_t f2bf(float f) {
  __bf16 h = (__bf16)f;
  return *(uint16_t*)&h;
}

// async global->LDS, 16B per lane. LDS dest must be wave-uniform base + lane*16.
__device__ __forceinline__ void gload16(const void* g, void* l) {
  __builtin_amdgcn_global_load_lds((const __attribute__((address_space(1))) void*)g,
                                   (__attribute__((address_space(3))) void*)l,
                                   16, 0, 0);
}

// ------------------------------------------- fp32->bf16, all 5 tensors in one
__global__ __launch_bounds__(256) void cvt_all(
    const float* __restrict__ x, const float* __restrict__ wq,
    const float* __restrict__ wk, const float* __restrict__ wv,
    const float* __restrict__ wo, uint16_t* __restrict__ xb,
    uint16_t* __restrict__ wqb, uint16_t* __restrict__ wkb,
    uint16_t* __restrict__ wvb, uint16_t* __restrict__ wob) {
  const int gid = blockIdx.x * 256 + threadIdx.x;  // 2097152 float4 chunks
  const float* src; uint16_t* dst; int off;
  if (gid < 1048576) {
    src = x; dst = xb; off = gid;
  } else {
    const int t = gid - 1048576;
    off = t & 262143;
    switch (t >> 18) {
      case 0: src = wq; dst = wqb; break;
      case 1: src = wk; dst = wkb; break;
      case 2: src = wv; dst = wvb; break;
      default: src = wo; dst = wob; break;
    }
  }
  const float4 f = ((const float4*)src)[off];
  uint64_t p = (uint64_t)f2bf(f.x) | ((uint64_t)f2bf(f.y) << 16) |
               ((uint64_t)f2bf(f.z) << 32) | ((uint64_t)f2bf(f.w) << 48);
  ((uint64_t*)dst)[off] = p;
}

// ------------------------------------------------- 128x128 GEMM, C = A*Bt^T
// BK=32, LDS double-buffered (32 KB), 256 threads = 4 waves (2x2 of 64x64,
// each wave 2x2 blocks of 32x32 MFMA), one barrier per k-tile, XOR swizzle.
template <bool OUT_BF16>
__device__ __forceinline__ void gemm128(const uint16_t* __restrict__ A,
                                        const uint16_t* __restrict__ Bt,
                                        const float* __restrict__ bias,
                                        float oscale,
                                        uint16_t* __restrict__ outb,
                                        float* __restrict__ outf) {
  __shared__ uint16_t sA[2][128 * 32];
  __shared__ uint16_t sB[2][128 * 32];
  const int tid = threadIdx.x;
  const int lane = tid & 63, w = tid >> 6;
  const int l31 = lane & 31, half = lane >> 5;
  const int m0 = blockIdx.y * 128, n0 = blockIdx.x * 128;
  const int wm = (w >> 1) * 64, wn = (w & 1) * 64;

  const int ch0 = tid, ch1 = tid + 256;
  const int r0 = ch0 >> 2, g0 = (((ch0 & 3) ^ (r0 & 3)) << 3);
  const int r1 = ch1 >> 2, g1 = (((ch1 & 3) ^ (r1 & 3)) << 3);
  const uint16_t* a0 = A + (size_t)(m0 + r0) * 1024 + g0;
  const uint16_t* a1 = A + (size_t)(m0 + r1) * 1024 + g1;
  const uint16_t* b0 = Bt + (size_t)(n0 + r0) * 1024 + g0;
  const uint16_t* b1 = Bt + (size_t)(n0 + r1) * 1024 + g1;

  gload16(a0, &sA[0][ch0 * 8]);
  gload16(a1, &sA[0][ch1 * 8]);
  gload16(b0, &sB[0][ch0 * 8]);
  gload16(b1, &sB[0][ch1 * 8]);

  f32x16 acc[2][2] = {};

  for (int kt = 0; kt < 32; ++kt) {
    __syncthreads();
    const int cur = kt & 1;
    if (kt < 31) {
      const int ko = (kt + 1) * 32;
      const int nxt = cur ^ 1;
      gload16(a0 + ko, &sA[nxt][ch0 * 8]);
      gload16(a1 + ko, &sA[nxt][ch1 * 8]);
      gload16(b0 + ko, &sB[nxt][ch0 * 8]);
      gload16(b1 + ko, &sB[nxt][ch1 * 8]);
    }
#pragma unroll
    for (int s = 0; s < 2; ++s) {
      const int c = s * 2 + half;
      bf16x8 af[2], bfr[2];
#pragma unroll
      for (int i = 0; i < 2; ++i) {
        const int arow = wm + i * 32 + l31;
        af[i] = *(const bf16x8*)&sA[cur][arow * 32 + ((c ^ (arow & 3)) << 3)];
      }
#pragma unroll
      for (int j = 0; j < 2; ++j) {
        const int brow = wn + j * 32 + l31;
        bfr[j] = *(const bf16x8*)&sB[cur][brow * 32 + ((c ^ (brow & 3)) << 3)];
      }
#pragma unroll
      for (int i = 0; i < 2; ++i)
#pragma unroll
        for (int j = 0; j < 2; ++j) acc[i][j] = MFMA32(af[i], bfr[j], acc[i][j]);
    }
  }

#pragma unroll
  for (int i = 0; i < 2; ++i) {
#pragma unroll
    for (int j = 0; j < 2; ++j) {
      const int gn = n0 + wn + j * 32 + l31;
      const float bv = bias[gn];
#pragma unroll
      for (int reg = 0; reg < 16; ++reg) {
        const int gm = m0 + wm + i * 32 + (reg & 3) + 8 * (reg >> 2) + 4 * half;
        const float v = (acc[i][j][reg] + bv) * oscale;
        const size_t idx = (size_t)gm * 1024 + gn;
        if constexpr (OUT_BF16) outb[idx] = f2bf(v);
        else outf[idx] = v;
      }
    }
  }
}

// Q is pre-scaled by (1/sqrt(dk)) * log2(e) so attn can use exp2 directly.
#define QSCALE 0.18033688011112042f

__global__ __launch_bounds__(256) void qkv_gemm(
    const uint16_t* __restrict__ xb, const uint16_t* __restrict__ wqb,
    const uint16_t* __restrict__ wkb, const uint16_t* __restrict__ wvb,
    const float* __restrict__ bq, const float* __restrict__ bk,
    const float* __restrict__ bv, uint16_t* __restrict__ qb,
    uint16_t* __restrict__ kb, uint16_t* __restrict__ vb) {
  const uint16_t* Bt; const float* bias; uint16_t* out; float sc;
  if (blockIdx.z == 0)      { Bt = wqb; bias = bq; out = qb; sc = QSCALE; }
  else if (blockIdx.z == 1) { Bt = wkb; bias = bk; out = kb; sc = 1.f; }
  else                      { Bt = wvb; bias = bv; out = vb; sc = 1.f; }
  gemm128<true>(xb, Bt, bias, sc, out, nullptr);
}

__global__ __launch_bounds__(256) void o_gemm(const uint16_t* __restrict__ ab,
                                              const uint16_t* __restrict__ wob,
                                              const float* __restrict__ bo,
                                              float* __restrict__ y) {
  gemm128<false>(ab, wob, bo, 1.f, nullptr, y);
}

// -------------------------------------- V transpose: (b,t,h,d) -> (b,h,d,t)
__global__ __launch_bounds__(256) void v_trans(const uint16_t* __restrict__ vb,
                                               uint16_t* __restrict__ vbT) {
  __shared__ uint16_t sT[64 * 136];
  const int tid = threadIdx.x;
  const int t0 = blockIdx.x * 128;
  const int h = blockIdx.y, b = blockIdx.z;
#pragma unroll
  for (int c = 0; c < 4; ++c) {
    const int idx = c * 256 + tid;
    const int t = idx >> 3, d8 = (idx & 7) * 8;
    u16x8 v = *(const u16x8*)&vb[(size_t)(b * 2048 + t0 + t) * 1024 + h * 64 + d8];
#pragma unroll
    for (int e = 0; e < 8; ++e) sT[(d8 + e) * 136 + t] = v[e];
  }
  __syncthreads();
  const size_t obase = ((size_t)(b * 16 + h) * 64) * 2048 + t0;
#pragma unroll
  for (int c = 0; c < 4; ++c) {
    const int idx = c * 256 + tid;
    const int d = idx >> 4, t8 = (idx & 15) * 8;
    u16x8 v = *(const u16x8*)&sT[d * 136 + t8];
    *(u16x8*)&vbT[obase + (size_t)d * 2048 + t8] = v;
  }
}

// --------------------------------------------------------- flash attention
// grid (hb=32, qt=16) = 512 blocks, XCD-swizzled (K/V L2-resident per XCD).
// 512 threads = 8 waves: rg = w&3 owns Q-rows [rg*32,+32); sh = w>>2 owns
// s-columns [sh*64,+64) of each 128-wide K/V tile. 32x32x16 MFMA.
// LDS 80 KB total -> 2 blocks/CU -> 16 waves/CU. One barrier per k-tile.
// Fixed-max softmax; partial acc_o/li summed across sh-pairs at epilogue.
__global__ __launch_bounds__(512, 4) void attn(const uint16_t* __restrict__ qb,
                                               const uint16_t* __restrict__ kb,
                                               const uint16_t* __restrict__ vbT,
                                               uint16_t* __restrict__ ab) {
  __shared__ __align__(16) uint16_t smem[40960];  // 80 KB
  uint16_t* sK = smem;           // [2][128*64]  32 KB  K rows s x dk
  uint16_t* sV = smem + 16384;   // [2][64*128]  32 KB  V^T rows d x s
  uint16_t* sP = smem + 32768;   // [8][32*32]   16 KB  per-wave P chunk
  const int tid = threadIdx.x;
  const int lane = tid & 63, w = tid >> 6;  // w in 0..7
  const int l31 = lane & 31, half = lane >> 5;
  const int rg = w & 3, sh = w >> 2;
  const int hb = blockIdx.x;
  const int h = hb & 15, b = hb >> 4;
  const int q0 = blockIdx.y * 128;
  const size_t qkbase = (size_t)b * 2048 * 1024 + (size_t)h * 64;
  const size_t vtbase = (size_t)hb * 64 * 2048;

  // staging: 1024 x 16B chunks per matrix per 128-s tile; 2 per thread each.
  const int ch0 = tid, ch1 = tid + 512;
  const int kr0 = ch0 >> 3, kg0 = (((ch0 & 7) ^ (kr0 & 7)) << 3);
  const int kr1 = ch1 >> 3, kg1 = (((ch1 & 7) ^ (kr1 & 7)) << 3);
  const int vr0 = ch0 >> 4, vg0 = (((ch0 & 15) ^ (vr0 & 15)) << 3);
  const int vr1 = ch1 >> 4, vg1 = (((ch1 & 15) ^ (vr1 & 15)) << 3);
  const uint16_t* k0 = kb + qkbase + (size_t)kr0 * 1024 + kg0;
  const uint16_t* k1 = kb + qkbase + (size_t)kr1 * 1024 + kg1;
  const uint16_t* v0 = vbT + vtbase + (size_t)vr0 * 2048 + vg0;
  const uint16_t* v1 = vbT + vtbase + (size_t)vr1 * 2048 + vg1;

  gload16(k0, sK + ch0 * 8);
  gload16(k1, sK + ch1 * 8);
  gload16(v0, sV + ch0 * 8);
  gload16(v1, sV + ch1 * 8);

  // Q A-frags: row = q0 + rg*32 + l31, k = s4*16 + half*8 + j (pre-scaled)
  bf16x8 qa[4];
  {
    const uint16_t* qrow =
        qb + qkbase + (size_t)(q0 + rg * 32 + l31) * 1024 + half * 8;
#pragma unroll
    for (int s4 = 0; s4 < 4; ++s4) qa[s4] = *(const bf16x8*)(qrow + s4 * 16);
  }

  f32x16 acc_o[2] = {};
  float li[16];
#pragma unroll
  for (int r = 0; r < 16; ++r) li[r] = 0.f;

  uint16_t* sPw = sP + w * 1024;
  __bf16* sPb = (__bf16*)sPw;

  for (int kt = 0; kt < 16; ++kt) {
    __syncthreads();  // tile kt staged (vmcnt drain); prev-buf readers done
    const int cur = kt & 1;
    if (kt < 15) {
      const size_t soK = (size_t)(kt + 1) * 128 * 1024;
      const int soV = (kt + 1) * 128;
      const int nxt = cur ^ 1;
      gload16(k0 + soK, sK + nxt * 8192 + ch0 * 8);
      gload16(k1 + soK, sK + nxt * 8192 + ch1 * 8);
      gload16(v0 + soV, sV + nxt * 8192 + ch0 * 8);
      gload16(v1 + soV, sV + nxt * 8192 + ch1 * 8);
    }
    const uint16_t* sKc = sK + cur * 8192;
    const uint16_t* sVc = sV + cur * 8192;

    // S = Q K^T over this wave's 64 s-cols: 8 MFMA
    f32x16 acc_s[2] = {};
#pragma unroll
    for (int s4 = 0; s4 < 4; ++s4) {
      const int c = s4 * 2 + half;
#pragma unroll
      for (int n = 0; n < 2; ++n) {
        const int brow = sh * 64 + n * 32 + l31;
        const bf16x8 kk =
            *(const bf16x8*)&sKc[brow * 64 + ((c ^ (brow & 7)) << 3)];
        acc_s[n] = MFMA32(qa[s4], kk, acc_s[n]);
      }
    }

    // per 32-s chunk: fixed-max softmax -> P chunk store -> PV (8 MFMA total)
#pragma unroll
    for (int n = 0; n < 2; ++n) {
#pragma unroll
      for (int reg = 0; reg < 16; ++reg) {
        const float p = __builtin_amdgcn_exp2f(acc_s[n][reg]);
        li[reg] += p;
        const int row = (reg & 3) + 8 * (reg >> 2) + 4 * half;
        sPb[row * 32 + (((l31 >> 3) ^ (row & 3)) << 3) + (l31 & 7)] = (__bf16)p;
      }
      // intra-wave DS ordering: stores above complete before reads below
#pragma unroll
      for (int st = 0; st < 2; ++st) {
        const int c2 = st * 2 + half;
        const bf16x8 pa = *(const bf16x8*)&sPw[l31 * 32 + ((c2 ^ (l31 & 3)) << 3)];
#pragma unroll
        for (int n2 = 0; n2 < 2; ++n2) {
          const int vrow = n2 * 32 + l31;
          const int c3 = sh * 8 + n * 4 + st * 2 + half;
          const bf16x8 vv =
              *(const bf16x8*)&sVc[vrow * 128 + ((c3 ^ (vrow & 15)) << 3)];
          acc_o[n2] = MFMA32(pa, vv, acc_o[n2]);
        }
      }
    }
  }

  // epilogue: combine sh=0/1 partials (pure add; fixed-max => no rescale)
  __syncthreads();  // all loop LDS reads done before reusing smem
  float* ep = (float*)smem;             // [4][2][16][64] = 32 KB
  float* epl = (float*)(smem + 16384);  // [4][16][64]    = 16 KB
  if (sh == 1) {
#pragma unroll
    for (int n2 = 0; n2 < 2; ++n2)
#pragma unroll
      for (int reg = 0; reg < 16; ++reg)
        ep[((rg * 2 + n2) * 16 + reg) * 64 + lane] = acc_o[n2][reg];
#pragma unroll
    for (int reg = 0; reg < 16; ++reg)
      epl[(rg * 16 + reg) * 64 + lane] = li[reg];
  }
  __syncthreads();
  if (sh == 0) {
#pragma unroll
    for (int n2 = 0; n2 < 2; ++n2)
#pragma unroll
      for (int reg = 0; reg < 16; ++reg)
        acc_o[n2][reg] += ep[((rg * 2 + n2) * 16 + reg) * 64 + lane];
#pragma unroll
    for (int reg = 0; reg < 16; ++reg) {
      float s = li[reg] + epl[(rg * 16 + reg) * 64 + lane];
#pragma unroll
      for (int o = 1; o < 32; o <<= 1) s += __shfl_xor(s, o);
      li[reg] = 1.f / s;
    }
#pragma unroll
    for (int n2 = 0; n2 < 2; ++n2)
#pragma unroll
      for (int reg = 0; reg < 16; ++reg) {
        const int row = q0 + rg * 32 + (reg & 3) + 8 * (reg >> 2) + 4 * half;
        const int col = h * 64 + n2 * 32 + l31;
        ab[(size_t)(b * 2048 + row) * 1024 + col] =
            f2bf(acc_o[n2][reg] * li[reg]);
      }
  }
}

// ------------------------------------------------ out = LN(x + y)*g + b
__global__ __launch_bounds__(256) void resid_ln(const float* __restrict__ x,
                                                const float* __restrict__ y,
                                                const float* __restrict__ gamma,
                                                const float* __restrict__ beta,
                                                float* __restrict__ out) {
  const int row = blockIdx.x, tid = threadIdx.x;
  const size_t base = (size_t)row * 1024 + tid * 4;
  const float4 xv = *(const float4*)(x + base);
  const float4 yv = *(const float4*)(y + base);
  const float a = xv.x + yv.x, b2 = xv.y + yv.y, c = xv.z + yv.z, d = xv.w + yv.w;
  float s = a + b2 + c + d;
#pragma unroll
  for (int o = 1; o < 64; o <<= 1) s += __shfl_xor(s, o);
  __shared__ float red[4];
  const int w = tid >> 6;
  if ((tid & 63) == 0) red[w] = s;
  __syncthreads();
  const float mu = (red[0] + red[1] + red[2] + red[3]) * (1.f / 1024.f);
  const float da = a - mu, db = b2 - mu, dc = c - mu, dd = d - mu;
  float sq = da * da + db * db + dc * dc + dd * dd;
#pragma unroll
  for (int o = 1; o < 64; o <<= 1) sq += __shfl_xor(sq, o);
  __syncthreads();
  if ((tid & 63) == 0) red[w] = sq;
  __syncthreads();
  const float var = (red[0] + red[1] + red[2] + red[3]) * (1.f / 1024.f);
  const float rs = rsqrtf(var + 1e-5f);
  const float4 g = *(const float4*)(gamma + tid * 4);
  const float4 bt = *(const float4*)(beta + tid * 4);
  float4 o4;
  o4.x = da * rs * g.x + bt.x;
  o4.y = db * rs * g.y + bt.y;
  o4.z = dc * rs * g.z + bt.z;
  o4.w = dd * rs * g.w + bt.w;
  *(float4*)(out + base) = o4;
}

// ---------------------------------------------------------------------------
extern "C" void kernel_launch(void* const* d_in, const int* in_sizes, int n_in,
                              void* d_out, int out_size, void* d_ws, size_t ws_size,
                              hipStream_t stream) {
  const float* x     = (const float*)d_in[0];
  const float* wq    = (const float*)d_in[1];
  const float* bq    = (const float*)d_in[2];
  const float* wk    = (const float*)d_in[3];
  const float* bk    = (const float*)d_in[4];
  const float* wv    = (const float*)d_in[5];
  const float* bv    = (const float*)d_in[6];
  const float* wo    = (const float*)d_in[7];
  const float* bo    = (const float*)d_in[8];
  const float* gamma = (const float*)d_in[9];
  const float* beta  = (const float*)d_in[10];
  float* out = (float*)d_out;
  char* ws = (char*)d_ws;
  const size_t MB = 1024 * 1024;
  uint16_t* xb  = (uint16_t*)(ws);            // [0,8) MB, dead after qkv_gemm
  uint16_t* ab  = xb;                         // attention out reuses xb
  uint16_t* wqb = (uint16_t*)(ws + 8 * MB);
  uint16_t* wkb = (uint16_t*)(ws + 10 * MB);
  uint16_t* wvb = (uint16_t*)(ws + 12 * MB);
  uint16_t* wob = (uint16_t*)(ws + 14 * MB);
  uint16_t* qb  = (uint16_t*)(ws + 16 * MB);  // [16,24)
  uint16_t* kb  = (uint16_t*)(ws + 24 * MB);  // [24,32)
  uint16_t* vb  = (uint16_t*)(ws + 32 * MB);  // [32,40), dead after v_trans
  uint16_t* vbT = (uint16_t*)(ws + 40 * MB);  // [40,48)
  float*    y   = (float*)(ws + 16 * MB);     // [16,32) fp32, over dead qb/kb

  cvt_all<<<8192, 256, 0, stream>>>(x, wq, wk, wv, wo, xb, wqb, wkb, wvb, wob);
  qkv_gemm<<<dim3(8, 32, 3), 256, 0, stream>>>(xb, wqb, wkb, wvb, bq, bk, bv, qb, kb, vb);
  v_trans<<<dim3(16, 16, 2), 256, 0, stream>>>(vb, vbT);
  attn<<<dim3(32, 16), 512, 0, stream>>>(qb, kb, vbT, ab);
  o_gemm<<<dim3(8, 32), 256, 0, stream>>>(ab, wob, bo, y);
  resid_ln<<<4096, 256, 0, stream>>>(x, y, gamma, beta, out);
}

// Round 9
// 207.935 us; speedup vs baseline: 1.0916x; 1.0916x over previous
//
#include <hip/hip_runtime.h>
#include <stdint.h>
#include <stddef.h>

// ---------------------------------------------------------------------------
// EinsumSelfAttention: LN(x + Attn(xWq^T+bq, xWk^T+bk, xWv^T+bv) Wo^T + bo)
// B=2 T=2048 D=1024 H=16 dk=64.  All matmuls via bf16 MFMA 32x32x16.
// Layouts: C/D (verified m74/m101): col=lane&31, row=(reg&3)+8*(reg>>2)+4*(lane>>5)
//          A/B frag: lane holds X[row/col=lane&31][k=(lane>>5)*8+j], j=0..7
// attn R9: S-TRANSPOSE trick. Compute S^T = K*Q^T (A=K, B=Q) so C has
// lane=q, regs=s. exp2+pack regs pairwise -> bf16x8 IS the B-operand of
// O^T = V^T * P^T, with V^T s-columns pre-permuted by
// sigma(j) = (j&3) + ((j>>2)&1)*8 + ((j>>3)&1)*4  (applied in v_trans).
// => NO P LDS round-trip (R6-R8 were DS-pipe-bound at ~400 DS-cyc/wave/tile;
// now 16 b128 reads only). li is a per-lane scalar.
// K-loops: async-LDS double buffer via global_load_lds, one barrier per tile.
// NO register-held tile data (R5: per-thread prefetch arrays -> scratch spill).
// ---------------------------------------------------------------------------

typedef __bf16 bf16_t;
typedef bf16_t bf16x8 __attribute__((ext_vector_type(8)));
typedef float f32x16 __attribute__((ext_vector_type(16)));
typedef uint16_t u16x8 __attribute__((ext_vector_type(8)));

#define MFMA32(a, b, c) __builtin_amdgcn_mfma_f32_32x32x16_bf16((a), (b), (c), 0, 0, 0)

__device__ __forceinline__ uint16_t f2bf(float f) {
  __bf16 h = (__bf16)f;
  return *(uint16_t*)&h;
}

// async global->LDS, 16B per lane. LDS dest must be wave-uniform base + lane*16.
__device__ __forceinline__ void gload16(const void* g, void* l) {
  __builtin_amdgcn_global_load_lds((const __attribute__((address_space(1))) void*)g,
                                   (__attribute__((address_space(3))) void*)l,
                                   16, 0, 0);
}

// ------------------------------------------- fp32->bf16, all 5 tensors in one
__global__ __launch_bounds__(256) void cvt_all(
    const float* __restrict__ x, const float* __restrict__ wq,
    const float* __restrict__ wk, const float* __restrict__ wv,
    const float* __restrict__ wo, uint16_t* __restrict__ xb,
    uint16_t* __restrict__ wqb, uint16_t* __restrict__ wkb,
    uint16_t* __restrict__ wvb, uint16_t* __restrict__ wob) {
  const int gid = blockIdx.x * 256 + threadIdx.x;  // 2097152 float4 chunks
  const float* src; uint16_t* dst; int off;
  if (gid < 1048576) {
    src = x; dst = xb; off = gid;
  } else {
    const int t = gid - 1048576;
    off = t & 262143;
    switch (t >> 18) {
      case 0: src = wq; dst = wqb; break;
      case 1: src = wk; dst = wkb; break;
      case 2: src = wv; dst = wvb; break;
      default: src = wo; dst = wob; break;
    }
  }
  const float4 f = ((const float4*)src)[off];
  uint64_t p = (uint64_t)f2bf(f.x) | ((uint64_t)f2bf(f.y) << 16) |
               ((uint64_t)f2bf(f.z) << 32) | ((uint64_t)f2bf(f.w) << 48);
  ((uint64_t*)dst)[off] = p;
}

// ------------------------------------------------- 128x128 GEMM, C = A*Bt^T
// BK=32, LDS double-buffered (32 KB), 256 threads = 4 waves (2x2 of 64x64,
// each wave 2x2 blocks of 32x32 MFMA), one barrier per k-tile, XOR swizzle.
template <bool OUT_BF16>
__device__ __forceinline__ void gemm128(const uint16_t* __restrict__ A,
                                        const uint16_t* __restrict__ Bt,
                                        const float* __restrict__ bias,
                                        float oscale,
                                        uint16_t* __restrict__ outb,
                                        float* __restrict__ outf) {
  __shared__ uint16_t sA[2][128 * 32];
  __shared__ uint16_t sB[2][128 * 32];
  const int tid = threadIdx.x;
  const int lane = tid & 63, w = tid >> 6;
  const int l31 = lane & 31, half = lane >> 5;
  const int m0 = blockIdx.y * 128, n0 = blockIdx.x * 128;
  const int wm = (w >> 1) * 64, wn = (w & 1) * 64;

  const int ch0 = tid, ch1 = tid + 256;
  const int r0 = ch0 >> 2, g0 = (((ch0 & 3) ^ (r0 & 3)) << 3);
  const int r1 = ch1 >> 2, g1 = (((ch1 & 3) ^ (r1 & 3)) << 3);
  const uint16_t* a0 = A + (size_t)(m0 + r0) * 1024 + g0;
  const uint16_t* a1 = A + (size_t)(m0 + r1) * 1024 + g1;
  const uint16_t* b0 = Bt + (size_t)(n0 + r0) * 1024 + g0;
  const uint16_t* b1 = Bt + (size_t)(n0 + r1) * 1024 + g1;

  gload16(a0, &sA[0][ch0 * 8]);
  gload16(a1, &sA[0][ch1 * 8]);
  gload16(b0, &sB[0][ch0 * 8]);
  gload16(b1, &sB[0][ch1 * 8]);

  f32x16 acc[2][2] = {};

  for (int kt = 0; kt < 32; ++kt) {
    __syncthreads();
    const int cur = kt & 1;
    if (kt < 31) {
      const int ko = (kt + 1) * 32;
      const int nxt = cur ^ 1;
      gload16(a0 + ko, &sA[nxt][ch0 * 8]);
      gload16(a1 + ko, &sA[nxt][ch1 * 8]);
      gload16(b0 + ko, &sB[nxt][ch0 * 8]);
      gload16(b1 + ko, &sB[nxt][ch1 * 8]);
    }
#pragma unroll
    for (int s = 0; s < 2; ++s) {
      const int c = s * 2 + half;
      bf16x8 af[2], bfr[2];
#pragma unroll
      for (int i = 0; i < 2; ++i) {
        const int arow = wm + i * 32 + l31;
        af[i] = *(const bf16x8*)&sA[cur][arow * 32 + ((c ^ (arow & 3)) << 3)];
      }
#pragma unroll
      for (int j = 0; j < 2; ++j) {
        const int brow = wn + j * 32 + l31;
        bfr[j] = *(const bf16x8*)&sB[cur][brow * 32 + ((c ^ (brow & 3)) << 3)];
      }
#pragma unroll
      for (int i = 0; i < 2; ++i)
#pragma unroll
        for (int j = 0; j < 2; ++j) acc[i][j] = MFMA32(af[i], bfr[j], acc[i][j]);
    }
  }

#pragma unroll
  for (int i = 0; i < 2; ++i) {
#pragma unroll
    for (int j = 0; j < 2; ++j) {
      const int gn = n0 + wn + j * 32 + l31;
      const float bv = bias[gn];
#pragma unroll
      for (int reg = 0; reg < 16; ++reg) {
        const int gm = m0 + wm + i * 32 + (reg & 3) + 8 * (reg >> 2) + 4 * half;
        const float v = (acc[i][j][reg] + bv) * oscale;
        const size_t idx = (size_t)gm * 1024 + gn;
        if constexpr (OUT_BF16) outb[idx] = f2bf(v);
        else outf[idx] = v;
      }
    }
  }
}

// Q is pre-scaled by (1/sqrt(dk)) * log2(e) so attn can use exp2 directly.
#define QSCALE 0.18033688011112042f

__global__ __launch_bounds__(256) void qkv_gemm(
    const uint16_t* __restrict__ xb, const uint16_t* __restrict__ wqb,
    const uint16_t* __restrict__ wkb, const uint16_t* __restrict__ wvb,
    const float* __restrict__ bq, const float* __restrict__ bk,
    const float* __restrict__ bv, uint16_t* __restrict__ qb,
    uint16_t* __restrict__ kb, uint16_t* __restrict__ vb) {
  const uint16_t* Bt; const float* bias; uint16_t* out; float sc;
  if (blockIdx.z == 0)      { Bt = wqb; bias = bq; out = qb; sc = QSCALE; }
  else if (blockIdx.z == 1) { Bt = wkb; bias = bk; out = kb; sc = 1.f; }
  else                      { Bt = wvb; bias = bv; out = vb; sc = 1.f; }
  gemm128<true>(xb, Bt, bias, sc, out, nullptr);
}

__global__ __launch_bounds__(256) void o_gemm(const uint16_t* __restrict__ ab,
                                              const uint16_t* __restrict__ wob,
                                              const float* __restrict__ bo,
                                              float* __restrict__ y) {
  gemm128<false>(ab, wob, bo, 1.f, nullptr, y);
}

// -------------------- V transpose: (b,t,h,d) -> (b,h,d,t), sigma-permuted s
// Within each 16-s block, output slot j holds s = (j&3)+((j>>2)&1)*8+((j>>3)&1)*4
// so that attn's PV A-operand (V^T) matches the register order of P^T packs.
__global__ __launch_bounds__(256) void v_trans(const uint16_t* __restrict__ vb,
                                               uint16_t* __restrict__ vbT) {
  __shared__ uint16_t sT[64 * 136];
  const int tid = threadIdx.x;
  const int t0 = blockIdx.x * 128;
  const int h = blockIdx.y, b = blockIdx.z;
#pragma unroll
  for (int c = 0; c < 4; ++c) {
    const int idx = c * 256 + tid;
    const int t = idx >> 3, d8 = (idx & 7) * 8;
    u16x8 v = *(const u16x8*)&vb[(size_t)(b * 2048 + t0 + t) * 1024 + h * 64 + d8];
#pragma unroll
    for (int e = 0; e < 8; ++e) sT[(d8 + e) * 136 + t] = v[e];
  }
  __syncthreads();
  const size_t obase = ((size_t)(b * 16 + h) * 64) * 2048 + t0;
#pragma unroll
  for (int c = 0; c < 4; ++c) {
    const int idx = c * 256 + tid;
    const int d = idx >> 4, t8 = (idx & 15) * 8;
    const int tb = t8 & ~15;              // 16-s block base
    const int add4 = (t8 & 8) ? 4 : 0;    // sigma for upper 8 slots
    u16x8 v;
#pragma unroll
    for (int e = 0; e < 8; ++e)
      v[e] = sT[d * 136 + tb + ((e & 3) + ((e >> 2) << 3)) + add4];
    *(u16x8*)&vbT[obase + (size_t)d * 2048 + t8] = v;
  }
}

// --------------------------------------------------------- flash attention
// grid (hb=32, qt=16) = 512 blocks, XCD-swizzled (K/V L2-resident per XCD).
// 512 threads = 8 waves: rg = w&3 owns Q-cols [rg*32,+32); sh = w>>2 owns
// s-rows [sh*64,+64) of each 128-s K/V tile. 32x32x16 MFMA, S^T orientation:
//   S^T = K*Q^T  (A=K rows s, B=Q cols q)  -> C: lane=q, regs=s
//   exp2+pack   -> P^T B-operand held in REGISTERS (no LDS round-trip)
//   O^T = V^T*P^T (A=V^T rows d, B=P^T)    -> C: lane=q, regs=d
// LDS: sK/sV double-buffered, 64 KB -> 2 blocks/CU. One barrier per tile.
// Fixed-max softmax; li is per-lane; partials summed across sh at epilogue.
__global__ __launch_bounds__(512, 4) void attn(const uint16_t* __restrict__ qb,
                                               const uint16_t* __restrict__ kb,
                                               const uint16_t* __restrict__ vbT,
                                               uint16_t* __restrict__ ab) {
  __shared__ __align__(16) uint16_t smem[32768];  // 64 KB
  uint16_t* sK = smem;           // [2][128*64]  32 KB  K rows s x dk
  uint16_t* sV = smem + 16384;   // [2][64*128]  32 KB  V^T rows d x s(sigma)
  const int tid = threadIdx.x;
  const int lane = tid & 63, w = tid >> 6;  // w in 0..7
  const int l31 = lane & 31, half = lane >> 5;
  const int rg = w & 3, sh = w >> 2;
  const int hb = blockIdx.x;
  const int h = hb & 15, b = hb >> 4;
  const int q0 = blockIdx.y * 128;
  const size_t qkbase = (size_t)b * 2048 * 1024 + (size_t)h * 64;
  const size_t vtbase = (size_t)hb * 64 * 2048;

  // staging: 1024 x 16B chunks per matrix per 128-s tile; 2 per thread each.
  const int ch0 = tid, ch1 = tid + 512;
  const int kr0 = ch0 >> 3, kg0 = (((ch0 & 7) ^ (kr0 & 7)) << 3);
  const int kr1 = ch1 >> 3, kg1 = (((ch1 & 7) ^ (kr1 & 7)) << 3);
  const int vr0 = ch0 >> 4, vg0 = (((ch0 & 15) ^ (vr0 & 15)) << 3);
  const int vr1 = ch1 >> 4, vg1 = (((ch1 & 15) ^ (vr1 & 15)) << 3);
  const uint16_t* k0 = kb + qkbase + (size_t)kr0 * 1024 + kg0;
  const uint16_t* k1 = kb + qkbase + (size_t)kr1 * 1024 + kg1;
  const uint16_t* v0 = vbT + vtbase + (size_t)vr0 * 2048 + vg0;
  const uint16_t* v1 = vbT + vtbase + (size_t)vr1 * 2048 + vg1;

  gload16(k0, sK + ch0 * 8);
  gload16(k1, sK + ch1 * 8);
  gload16(v0, sV + ch0 * 8);
  gload16(v1, sV + ch1 * 8);

  // Q B-frags in registers: col q = q0+rg*32+l31, k = s4*16 + half*8 + j
  bf16x8 qa[4];
  {
    const uint16_t* qrow =
        qb + qkbase + (size_t)(q0 + rg * 32 + l31) * 1024 + half * 8;
#pragma unroll
    for (int s4 = 0; s4 < 4; ++s4) qa[s4] = *(const bf16x8*)(qrow + s4 * 16);
  }

  f32x16 acc_o[2] = {};  // O^T partial: regs=d (md*32 + c-row map), lane=q
  float li = 0.f;        // per-lane (q) softmax denominator partial

  for (int kt = 0; kt < 16; ++kt) {
    __syncthreads();  // tile kt staged (vmcnt drain); prev-buf readers done
    const int cur = kt & 1;
    if (kt < 15) {
      const size_t soK = (size_t)(kt + 1) * 128 * 1024;
      const int soV = (kt + 1) * 128;
      const int nxt = cur ^ 1;
      gload16(k0 + soK, sK + nxt * 8192 + ch0 * 8);
      gload16(k1 + soK, sK + nxt * 8192 + ch1 * 8);
      gload16(v0 + soV, sV + nxt * 8192 + ch0 * 8);
      gload16(v1 + soV, sV + nxt * 8192 + ch1 * 8);
    }
    const uint16_t* sKc = sK + cur * 8192;
    const uint16_t* sVc = sV + cur * 8192;

#pragma unroll
    for (int mblk = 0; mblk < 2; ++mblk) {  // 32-s chunk within wave's 64 s
      // S^T: A=K rows s, B=Q. 4 MFMA
      f32x16 accs = {};
#pragma unroll
      for (int s4 = 0; s4 < 4; ++s4) {
        const int c = s4 * 2 + half;
        const int srow = sh * 64 + mblk * 32 + l31;
        const bf16x8 kk =
            *(const bf16x8*)&sKc[srow * 64 + ((c ^ (srow & 7)) << 3)];
        accs = MFMA32(kk, qa[s4], accs);
      }
      // fixed-max softmax + pack into P^T B-operands (registers only)
      bf16x8 bp0, bp1;
#pragma unroll
      for (int reg = 0; reg < 8; ++reg) {
        const float p = __builtin_amdgcn_exp2f(accs[reg]);
        li += p;
        bp0[reg] = (__bf16)p;
      }
#pragma unroll
      for (int reg = 8; reg < 16; ++reg) {
        const float p = __builtin_amdgcn_exp2f(accs[reg]);
        li += p;
        bp1[reg - 8] = (__bf16)p;
      }
      // O^T += V^T * P^T : A=V^T rows d (sigma-ordered s-cols). 4 MFMA
#pragma unroll
      for (int t = 0; t < 2; ++t) {
        const bf16x8 bp = t ? bp1 : bp0;
        const int cc = sh * 8 + mblk * 4 + t * 2 + half;
#pragma unroll
        for (int md = 0; md < 2; ++md) {
          const int vrow = md * 32 + l31;
          const bf16x8 vv =
              *(const bf16x8*)&sVc[vrow * 128 + ((cc ^ (vrow & 15)) << 3)];
          acc_o[md] = MFMA32(vv, bp, acc_o[md]);
        }
      }
    }
  }

  // epilogue: combine sh partials (pure add; fixed-max => no rescale)
  __syncthreads();  // all loop LDS reads done before reusing smem
  float* ep = (float*)smem;                  // [4][2][16][64] fp32 = 32 KB
  float* epl = (float*)(smem + 16384);       // [4][64] fp32 = 1 KB
  if (sh == 1) {
#pragma unroll
    for (int md = 0; md < 2; ++md)
#pragma unroll
      for (int reg = 0; reg < 16; ++reg)
        ep[((rg * 2 + md) * 16 + reg) * 64 + lane] = acc_o[md][reg];
    epl[rg * 64 + lane] = li;
  }
  __syncthreads();
  if (sh == 0) {
#pragma unroll
    for (int md = 0; md < 2; ++md)
#pragma unroll
      for (int reg = 0; reg < 16; ++reg)
        acc_o[md][reg] += ep[((rg * 2 + md) * 16 + reg) * 64 + lane];
    li += epl[rg * 64 + lane];
    li += __shfl_xor(li, 32);  // both halves hold the same q
    const float inv = 1.f / li;
    const int row = q0 + rg * 32 + l31;
    uint16_t* const obase = ab + (size_t)(b * 2048 + row) * 1024 + h * 64;
#pragma unroll
    for (int md = 0; md < 2; ++md)
#pragma unroll
      for (int g = 0; g < 4; ++g) {
        // regs 4g..4g+3 -> d = md*32 + 8g + 4*half + (0..3): one 8B store
        uint64_t pk = 0;
#pragma unroll
        for (int e = 0; e < 4; ++e)
          pk |= (uint64_t)f2bf(acc_o[md][g * 4 + e] * inv) << (16 * e);
        *(uint64_t*)(obase + md * 32 + g * 8 + half * 4) = pk;
      }
  }
}

// ------------------------------------------------ out = LN(x + y)*g + b
__global__ __launch_bounds__(256) void resid_ln(const float* __restrict__ x,
                                                const float* __restrict__ y,
                                                const float* __restrict__ gamma,
                                                const float* __restrict__ beta,
                                                float* __restrict__ out) {
  const int row = blockIdx.x, tid = threadIdx.x;
  const size_t base = (size_t)row * 1024 + tid * 4;
  const float4 xv = *(const float4*)(x + base);
  const float4 yv = *(const float4*)(y + base);
  const float a = xv.x + yv.x, b2 = xv.y + yv.y, c = xv.z + yv.z, d = xv.w + yv.w;
  float s = a + b2 + c + d;
#pragma unroll
  for (int o = 1; o < 64; o <<= 1) s += __shfl_xor(s, o);
  __shared__ float red[4];
  const int w = tid >> 6;
  if ((tid & 63) == 0) red[w] = s;
  __syncthreads();
  const float mu = (red[0] + red[1] + red[2] + red[3]) * (1.f / 1024.f);
  const float da = a - mu, db = b2 - mu, dc = c - mu, dd = d - mu;
  float sq = da * da + db * db + dc * dc + dd * dd;
#pragma unroll
  for (int o = 1; o < 64; o <<= 1) sq += __shfl_xor(sq, o);
  __syncthreads();
  if ((tid & 63) == 0) red[w] = sq;
  __syncthreads();
  const float var = (red[0] + red[1] + red[2] + red[3]) * (1.f / 1024.f);
  const float rs = rsqrtf(var + 1e-5f);
  const float4 g = *(const float4*)(gamma + tid * 4);
  const float4 bt = *(const float4*)(beta + tid * 4);
  float4 o4;
  o4.x = da * rs * g.x + bt.x;
  o4.y = db * rs * g.y + bt.y;
  o4.z = dc * rs * g.z + bt.z;
  o4.w = dd * rs * g.w + bt.w;
  *(float4*)(out + base) = o4;
}

// ---------------------------------------------------------------------------
extern "C" void kernel_launch(void* const* d_in, const int* in_sizes, int n_in,
                              void* d_out, int out_size, void* d_ws, size_t ws_size,
                              hipStream_t stream) {
  const float* x     = (const float*)d_in[0];
  const float* wq    = (const float*)d_in[1];
  const float* bq    = (const float*)d_in[2];
  const float* wk    = (const float*)d_in[3];
  const float* bk    = (const float*)d_in[4];
  const float* wv    = (const float*)d_in[5];
  const float* bv    = (const float*)d_in[6];
  const float* wo    = (const float*)d_in[7];
  const float* bo    = (const float*)d_in[8];
  const float* gamma = (const float*)d_in[9];
  const float* beta  = (const float*)d_in[10];
  float* out = (float*)d_out;
  char* ws = (char*)d_ws;
  const size_t MB = 1024 * 1024;
  uint16_t* xb  = (uint16_t*)(ws);            // [0,8) MB, dead after qkv_gemm
  uint16_t* ab  = xb;                         // attention out reuses xb
  uint16_t* wqb = (uint16_t*)(ws + 8 * MB);
  uint16_t* wkb = (uint16_t*)(ws + 10 * MB);
  uint16_t* wvb = (uint16_t*)(ws + 12 * MB);
  uint16_t* wob = (uint16_t*)(ws + 14 * MB);
  uint16_t* qb  = (uint16_t*)(ws + 16 * MB);  // [16,24)
  uint16_t* kb  = (uint16_t*)(ws + 24 * MB);  // [24,32)
  uint16_t* vb  = (uint16_t*)(ws + 32 * MB);  // [32,40), dead after v_trans
  uint16_t* vbT = (uint16_t*)(ws + 40 * MB);  // [40,48)
  float*    y   = (float*)(ws + 16 * MB);     // [16,32) fp32, over dead qb/kb

  cvt_all<<<8192, 256, 0, stream>>>(x, wq, wk, wv, wo, xb, wqb, wkb, wvb, wob);
  qkv_gemm<<<dim3(8, 32, 3), 256, 0, stream>>>(xb, wqb, wkb, wvb, bq, bk, bv, qb, kb, vb);
  v_trans<<<dim3(16, 16, 2), 256, 0, stream>>>(vb, vbT);
  attn<<<dim3(32, 16), 512, 0, stream>>>(qb, kb, vbT, ab);
  o_gemm<<<dim3(8, 32), 256, 0, stream>>>(ab, wob, bo, y);
  resid_ln<<<4096, 256, 0, stream>>>(x, y, gamma, beta, out);
}